// Round 5
// baseline (182.142 us; speedup 1.0000x reference)
//
#include <hip/hip_runtime.h>

// HashEmbedding: out[b,s,:] = embedding[hashed_ids[b,s], :]  (pure gather)
//
// DTYPES (settled R1-R4): hashed_ids int32, embedding/out float32.
// Row = 1024 f32 = 4096 B = 256 x 16 B chunks.
//
// R4 post-mortem: one 16B load+store per one-shot thread = latency-bound
// (179 us vs ~35 us roofline). Fix: grid-stride + 4-way unroll (4 outstanding
// gathers per lane), non-temporal stores (keep L2 for the 41 MB table, not
// the 134 MB write-once output), 2048 blocks.

#define ROW_SHIFT   8                   // 256 chunks per row
#define ROW_MASK    255
#define NUM_BUCKETS 10000

typedef unsigned int v4u __attribute__((ext_vector_type(4)));

__global__ __launch_bounds__(256) void HashEmbedding_46136538693901_kernel(
    const int* __restrict__ hashed_ids,   // [B*S] int32, values in [0, 10000)
    const v4u* __restrict__ emb,          // [NUM_BUCKETS * 256]
    v4u* __restrict__ out,                // [B*S * 256]
    int n_vec)                            // B*S * 256 = 8,388,608
{
    const int tid    = blockIdx.x * blockDim.x + threadIdx.x;
    const int stride = gridDim.x * blockDim.x;          // 524,288

    int base = tid;
    // Fast path: 4 independent gathers in flight per iteration.
    for (; base + 3 * stride < n_vec; base += 4 * stride) {
        const int i0 = base, i1 = base + stride, i2 = base + 2 * stride, i3 = base + 3 * stride;

        int x0 = hashed_ids[i0 >> ROW_SHIFT];
        int x1 = hashed_ids[i1 >> ROW_SHIFT];
        int x2 = hashed_ids[i2 >> ROW_SHIFT];
        int x3 = hashed_ids[i3 >> ROW_SHIFT];
        if ((unsigned)x0 >= (unsigned)NUM_BUCKETS) x0 = 0;
        if ((unsigned)x1 >= (unsigned)NUM_BUCKETS) x1 = 0;
        if ((unsigned)x2 >= (unsigned)NUM_BUCKETS) x2 = 0;
        if ((unsigned)x3 >= (unsigned)NUM_BUCKETS) x3 = 0;

        v4u v0 = emb[(size_t)x0 * 256 + (i0 & ROW_MASK)];
        v4u v1 = emb[(size_t)x1 * 256 + (i1 & ROW_MASK)];
        v4u v2 = emb[(size_t)x2 * 256 + (i2 & ROW_MASK)];
        v4u v3 = emb[(size_t)x3 * 256 + (i3 & ROW_MASK)];

        __builtin_nontemporal_store(v0, &out[i0]);
        __builtin_nontemporal_store(v1, &out[i1]);
        __builtin_nontemporal_store(v2, &out[i2]);
        __builtin_nontemporal_store(v3, &out[i3]);
    }
    // Tail (unused when n_vec % (4*stride) == 0, kept for safety).
    for (; base < n_vec; base += stride) {
        int x = hashed_ids[base >> ROW_SHIFT];
        if ((unsigned)x >= (unsigned)NUM_BUCKETS) x = 0;
        v4u v = emb[(size_t)x * 256 + (base & ROW_MASK)];
        __builtin_nontemporal_store(v, &out[base]);
    }
}

extern "C" void kernel_launch(void* const* d_in, const int* in_sizes, int n_in,
                              void* d_out, int out_size, void* d_ws, size_t ws_size,
                              hipStream_t stream) {
    // setup_inputs dict order: input_ids [B*S] (unused), hashed_ids [B*S] i32,
    // embedding [NUM_BUCKETS*1024] f32.
    const int* hashed = (const int*)d_in[1];
    const v4u* emb    = (const v4u*)d_in[2];
    v4u*       out    = (v4u*)d_out;

    int n_tokens = in_sizes[1];            // 32768
    int n_vec    = n_tokens * 256;         // 8,388,608 (== out_size/4)

    const int block = 256;
    const int grid  = 2048;                // 16 chunks/thread, 4-way unrolled
    HashEmbedding_46136538693901_kernel<<<grid, block, 0, stream>>>(hashed, emb, out, n_vec);
}